// Round 4
// baseline (752.010 us; speedup 1.0000x reference)
//
#include <hip/hip_runtime.h>

// MS Deformable Attention 3D — R4.
// K1 valproj: MFMA, spill-free staging, vectorized uint4 epilogue.
// K2 attn: MFMA GEMMs; gather with dwordx2 channel-quad loads, compressed
//          12B records in skewed LDS tables, parallel softmax.

#define EE   256
#define HH   8
#define LL   4
#define NQq  10000
#define BSB  2
#define LENV 13294
#define MQ   16
#define ROWS_V (BSB * LENV)   // 26588

typedef unsigned short u16;
typedef unsigned int   u32;
typedef __attribute__((ext_vector_type(8))) short bf16x8;
typedef __attribute__((ext_vector_type(4))) float f32x4;

__device__ __forceinline__ u32 bf16_of(float f) {
  u32 u = __float_as_uint(f);
  return (u + 0x7FFFu + ((u >> 16) & 1u)) >> 16;   // RNE
}
__device__ __forceinline__ float bflo(u32 u) { return __uint_as_float(u << 16); }
__device__ __forceinline__ float bfhi(u32 u) { return __uint_as_float(u & 0xFFFF0000u); }

__device__ __forceinline__ uint4 pack8(const float* f) {
  uint4 u;
  u.x = bf16_of(f[0]) | (bf16_of(f[1]) << 16);
  u.y = bf16_of(f[2]) | (bf16_of(f[3]) << 16);
  u.z = bf16_of(f[4]) | (bf16_of(f[5]) << 16);
  u.w = bf16_of(f[6]) | (bf16_of(f[7]) << 16);
  return u;
}

// ---- K0: weights -> bf16 B-fragment layout ----------------------------------
__global__ __launch_bounds__(64) void k_prep(
    const float* __restrict__ W_off, const float* __restrict__ W_attn,
    const float* __restrict__ W_val, const float* __restrict__ W_out,
    u16* __restrict__ wcat, u16* __restrict__ wval, u16* __restrict__ wout) {
  const int tile = blockIdx.x >> 3, s = blockIdx.x & 7;
  const int l = threadIdx.x, quad = l >> 4, r16 = l & 15;
  float f[8];
  u16* dst;
  if (tile < 48) {            // concat(W_off[256x512], W_attn[256x256])
    int col = tile * 16 + r16;
#pragma unroll
    for (int j = 0; j < 8; ++j) {
      int k = s * 32 + quad * 8 + j;
      f[j] = (col < 512) ? W_off[k * 512 + col] : W_attn[k * 256 + (col - 512)];
    }
    dst = wcat + ((tile * 8 + s) * 64 + l) * 8;
  } else if (tile < 64) {     // W_val
    int col = (tile - 48) * 16 + r16;
#pragma unroll
    for (int j = 0; j < 8; ++j) f[j] = W_val[(s * 32 + quad * 8 + j) * 256 + col];
    dst = wval + (((tile - 48) * 8 + s) * 64 + l) * 8;
  } else {                    // W_out
    int col = (tile - 64) * 16 + r16;
#pragma unroll
    for (int j = 0; j < 8; ++j) f[j] = W_out[(s * 32 + quad * 8 + j) * 256 + col];
    dst = wout + (((tile - 64) * 8 + s) * 64 + l) * 8;
  }
  *(uint4*)dst = pack8(f);
}

// ---- K1: value projection ---------------------------------------------------
__global__ __launch_bounds__(256) void k_valproj(
    const float* __restrict__ value, const float* __restrict__ b_val,
    const u16* __restrict__ wval, u16* __restrict__ v_ws) {
  __shared__ __align__(16) u16 sA[64][264];
  const int tid = threadIdx.x;
  const int g0 = blockIdx.x * 64;
  // staging: rolled (avoid 16 concurrent float4 -> spills)
#pragma unroll 2
  for (int ch = 0; ch < 8; ++ch) {
    int row = ch * 8 + (tid >> 5);
    int col = (tid & 31) * 8;
    int g = g0 + row;
    uint4 pk = {0u, 0u, 0u, 0u};
    if (g < ROWS_V) {
      float4 a = *(const float4*)(value + (long)g * 256 + col);
      float4 c = *(const float4*)(value + (long)g * 256 + col + 4);
      float fv[8] = {a.x, a.y, a.z, a.w, c.x, c.y, c.z, c.w};
      pk = pack8(fv);
    }
    *(uint4*)&sA[row][col] = pk;
  }
  __syncthreads();
  const int wave = tid >> 6, lane = tid & 63, quad = lane >> 4, r16 = lane & 15;
  f32x4 acc[4][4] = {};
  for (int s = 0; s < 8; ++s) {
    bf16x8 af[4];
#pragma unroll
    for (int mt = 0; mt < 4; ++mt)
      af[mt] = *(const bf16x8*)&sA[mt * 16 + r16][s * 32 + quad * 8];
#pragma unroll
    for (int nt = 0; nt < 4; ++nt) {
      bf16x8 bfg = *(const bf16x8*)(wval + (((wave * 4 + nt) * 8 + s) * 64 + lane) * 8);
#pragma unroll
      for (int mt = 0; mt < 4; ++mt)
        acc[nt][mt] = __builtin_amdgcn_mfma_f32_16x16x32_bf16(af[mt], bfg, acc[nt][mt], 0, 0, 0);
    }
  }
  __syncthreads();
#pragma unroll
  for (int nt = 0; nt < 4; ++nt) {
    int col = (wave * 4 + nt) * 16 + r16;
    float bias = b_val[col];
#pragma unroll
    for (int mt = 0; mt < 4; ++mt)
#pragma unroll
      for (int rr = 0; rr < 4; ++rr)
        sA[mt * 16 + quad * 4 + rr][col] = (u16)bf16_of(acc[nt][mt][rr] + bias);
  }
  __syncthreads();
  // vectorized write: thread -> 16B of one row per pass
  {
    int r0 = tid >> 5;          // 0..7
    int col = (tid & 31) * 8;   // u16 col, 16B aligned
    int h = col >> 5, c = col & 31;
#pragma unroll 2
    for (int p = 0; p < 8; ++p) {
      int r = p * 8 + r0;
      int g = g0 + r;
      if (g < ROWS_V) {
        int bb = (g >= LENV) ? 1 : 0;
        int pix = g - (bb ? LENV : 0);
        *(uint4*)(v_ws + (((long)(bb * 8 + h) * LENV + pix) * 32 + c)) =
            *(const uint4*)&sA[r][col];
      }
    }
  }
}

// ---- K2: 16 queries/block, 512 threads --------------------------------------
__global__ __launch_bounds__(512, 4) void k_attn(
    const float* __restrict__ query, const float* __restrict__ query_pos,
    const float* __restrict__ refpts,
    const float* __restrict__ b_off, const float* __restrict__ b_attn,
    const float* __restrict__ b_out,
    const u16* __restrict__ wcat, const u16* __restrict__ wout,
    const u16* __restrict__ v_ws, float* __restrict__ out) {
  __shared__ __align__(16) char smem[49536];
  u16   (*sQ)[264] = (u16(*)[264])smem;     // staged q (bf16)
  float (*sC)[772] = (float(*)[772])smem;   // GEMM1 C (alias, after sQ dead)
  uint2* sWt = (uint2*)smem;                // weights table [skewed 4111]
  u32*   sOf = (u32*)(smem + 32888);        // offset table  [skewed 4111]
  u16   (*sO)[264] = (u16(*)[264])smem;     // gather output (after tables dead)

  const int tid = threadIdx.x;
  const int g0 = blockIdx.x * MQ;
  const int b = g0 / NQq;
  const int q0 = g0 - b * NQq;
  const int wave = tid >> 6, lane = tid & 63, quad = lane >> 4, r16 = lane & 15;

  // phase 0: stage q = query + query_pos (bf16)
  {
    int row = tid >> 5, col = (tid & 31) * 8;
    long base = ((long)(b * NQq + q0 + row)) * 256 + col;
    float4 a0 = *(const float4*)(query + base);
    float4 a1 = *(const float4*)(query + base + 4);
    float4 p0 = *(const float4*)(query_pos + base);
    float4 p1 = *(const float4*)(query_pos + base + 4);
    float fv[8] = {a0.x + p0.x, a0.y + p0.y, a0.z + p0.z, a0.w + p0.w,
                   a1.x + p1.x, a1.y + p1.y, a1.z + p1.z, a1.w + p1.w};
    *(uint4*)&sQ[row][col] = pack8(fv);
  }
  __syncthreads();

  // phase 1: C[16][768] = q @ concat(W_off, W_attn)
  f32x4 acc[6] = {};
  for (int s = 0; s < 8; ++s) {
    bf16x8 af = *(const bf16x8*)&sQ[r16][s * 32 + quad * 8];
#pragma unroll
    for (int t6 = 0; t6 < 6; ++t6) {
      int tile = wave * 6 + t6;
      bf16x8 bfg = *(const bf16x8*)(wcat + ((tile * 8 + s) * 64 + lane) * 8);
      acc[t6] = __builtin_amdgcn_mfma_f32_16x16x32_bf16(af, bfg, acc[t6], 0, 0, 0);
    }
  }
  __syncthreads();                       // sQ dead
#pragma unroll
  for (int t6 = 0; t6 < 6; ++t6) {
    int col = (wave * 6 + t6) * 16 + r16;
#pragma unroll
    for (int rr = 0; rr < 4; ++rr)
      sC[quad * 4 + rr][col] = acc[t6][rr];
  }
  __syncthreads();

  // phase 2: parallel softmax per (m,h): 4 lanes x 8 logits, shuffle-reduce
  {
    int m = tid >> 5, h = (tid >> 2) & 7, j = tid & 3;
    float* p = &sC[m][512 + h * 32 + j * 8];
    const float* ba = b_attn + h * 32 + j * 8;
    float v[8];
    float mx = -1e30f;
#pragma unroll
    for (int k = 0; k < 8; ++k) { v[k] = p[k] + ba[k]; mx = fmaxf(mx, v[k]); }
    mx = fmaxf(mx, __shfl_xor(mx, 1));
    mx = fmaxf(mx, __shfl_xor(mx, 2));
    float sum = 0.f;
#pragma unroll
    for (int k = 0; k < 8; ++k) { v[k] = __expf(v[k] - mx); sum += v[k]; }
    sum += __shfl_xor(sum, 1);
    sum += __shfl_xor(sum, 2);
    float inv = 1.f / sum;
#pragma unroll
    for (int k = 0; k < 8; ++k) p[k] = v[k] * inv;
  }
  __syncthreads();

  // phase 3: build compressed records (regs bridge sC -> table alias)
  uint2 wts[8];
  u32 obs[8];
  {
    const int s = tid & 255, mh = tid >> 8;
    const int l = (s >> 3) & 3;
    const int WlI[4] = {100, 50, 25, 13};
    const int baseI[4] = {0, 10000, 12500, 13125};
    const int Wl = WlI[l], Hl = WlI[l], base = baseI[l];
    const float WlF = (float)Wl;
    const float box = b_off[2 * s], boy = b_off[2 * s + 1];
#pragma unroll
    for (int mm = 0; mm < 8; ++mm) {
      int m = mh * 8 + mm;
      float w = sC[m][512 + s];
      float ax = sC[m][2 * s], ay = sC[m][2 * s + 1];
      float2 rp = *(const float2*)(refpts + (((long)(b * NQq + q0 + m)) * LL + l) * 2);
      float x = rp.x * WlF + (ax + box) - 0.5f;
      float y = rp.y * WlF + (ay + boy) - 0.5f;
      float fx0 = floorf(x), fy0 = floorf(y);
      int x0 = (int)fx0, y0 = (int)fy0;
      float fx = x - fx0, fy = y - fy0;
      bool xv0 = (x0 >= 0) & (x0 < Wl);
      bool xv1 = (x0 >= -1) & (x0 < Wl - 1);
      bool yv0 = (y0 >= 0) & (y0 < Hl);
      bool yv1 = (y0 >= -1) & (y0 < Hl - 1);
      float w00 = w * (1.f - fx) * (1.f - fy) * (float)(xv0 & yv0);
      float w01 = w * fx * (1.f - fy) * (float)(xv1 & yv0);
      float w10 = w * (1.f - fx) * fy * (float)(xv0 & yv1);
      float w11 = w * fx * fy * (float)(xv1 & yv1);
      int x0c = min(max(x0, 0), Wl - 1);
      int x1c = min(max(x0 + 1, 0), Wl - 1);
      int y0c = min(max(y0, 0), Hl - 1);
      int y1c = min(max(y0 + 1, 0), Hl - 1);
      u32 o00 = (u32)(base + y0c * Wl + x0c) * 32u;           // < 2^20
      u32 dxb = (x1c > x0c) ? 1u : 0u;
      u32 dyb = (y1c > y0c) ? 1u : 0u;
      wts[mm].x = bf16_of(w00) | (bf16_of(w01) << 16);
      wts[mm].y = bf16_of(w10) | (bf16_of(w11) << 16);
      obs[mm] = o00 | (dxb << 31) | (dyb << 30);
    }
  }
  __syncthreads();                       // sC dead
  {
    const int s = tid & 255, mh = tid >> 8;
#pragma unroll
    for (int mm = 0; mm < 8; ++mm) {
      int idx = (mh * 8 + mm) * 257 + s;  // skew: m-stride 257 -> distinct banks
      sWt[idx] = wts[mm];
      sOf[idx] = obs[mm];
    }
  }
  __syncthreads();

  // phase 4: gather — wave = head h; lane = (m-pair mg, channel-quad cq)
  const int h = tid >> 6, mg = (tid >> 3) & 7, cq = tid & 7;
  float oacc[2][4] = {};
  {
    const u32 hcb = ((u32)(b * 8 + h) * (u32)LENV) * 32u + (u32)(cq * 4);
    const int WlI[4] = {100, 50, 25, 13};
#pragma unroll
    for (int lvl = 0; lvl < 4; ++lvl) {
      const u32 dyv = (u32)WlI[lvl] * 32u;
      for (int ii = 0; ii < 8; ++ii) {
        int sbase = h * 32 + lvl * 8 + ii;
#pragma unroll
        for (int mm = 0; mm < 2; ++mm) {
          int idx = (mg * 2 + mm) * 257 + sbase;
          uint2 wr = sWt[idx];
          u32 ob = sOf[idx];
          u32 o00 = hcb + (ob & 0x000FFFFFu);
          u32 dx = (ob & 0x80000000u) ? 32u : 0u;
          u32 dy = (ob & 0x40000000u) ? dyv : 0u;
          uint2 v00 = *(const uint2*)(v_ws + o00);
          uint2 v01 = *(const uint2*)(v_ws + o00 + dx);
          uint2 v10 = *(const uint2*)(v_ws + o00 + dy);
          uint2 v11 = *(const uint2*)(v_ws + o00 + dx + dy);
          float w00 = bflo(wr.x), w01 = bfhi(wr.x);
          float w10 = bflo(wr.y), w11 = bfhi(wr.y);
          oacc[mm][0] += w00 * bflo(v00.x) + w01 * bflo(v01.x) + w10 * bflo(v10.x) + w11 * bflo(v11.x);
          oacc[mm][1] += w00 * bfhi(v00.x) + w01 * bfhi(v01.x) + w10 * bfhi(v10.x) + w11 * bfhi(v11.x);
          oacc[mm][2] += w00 * bflo(v00.y) + w01 * bflo(v01.y) + w10 * bflo(v10.y) + w11 * bflo(v11.y);
          oacc[mm][3] += w00 * bfhi(v00.y) + w01 * bfhi(v01.y) + w10 * bfhi(v10.y) + w11 * bfhi(v11.y);
        }
      }
    }
  }
  __syncthreads();                       // tables dead
  {
    int col = h * 32 + cq * 4;
#pragma unroll
    for (int mm = 0; mm < 2; ++mm) {
      int m = mg * 2 + mm;
      u32 p0 = bf16_of(oacc[mm][0]) | (bf16_of(oacc[mm][1]) << 16);
      u32 p1 = bf16_of(oacc[mm][2]) | (bf16_of(oacc[mm][3]) << 16);
      *(u32*)&sO[m][col] = p0;
      *(u32*)&sO[m][col + 2] = p1;
    }
  }
  __syncthreads();

  // phase 5: out = gathered @ W_out + b_out
  f32x4 acc2[2] = {};
  for (int s = 0; s < 8; ++s) {
    bf16x8 af = *(const bf16x8*)&sO[r16][s * 32 + quad * 8];
#pragma unroll
    for (int t2 = 0; t2 < 2; ++t2) {
      int tile = wave * 2 + t2;
      bf16x8 bfg = *(const bf16x8*)(wout + ((tile * 8 + s) * 64 + lane) * 8);
      acc2[t2] = __builtin_amdgcn_mfma_f32_16x16x32_bf16(af, bfg, acc2[t2], 0, 0, 0);
    }
  }
#pragma unroll
  for (int t2 = 0; t2 < 2; ++t2) {
    int col = (wave * 2 + t2) * 16 + r16;
    float bias = b_out[col];
#pragma unroll
    for (int rr = 0; rr < 4; ++rr) {
      int row = quad * 4 + rr;
      out[((long)(b * NQq + q0 + row)) * 256 + col] = acc2[t2][rr] + bias;
    }
  }
}

extern "C" void kernel_launch(void* const* d_in, const int* in_sizes, int n_in,
                              void* d_out, int out_size, void* d_ws, size_t ws_size,
                              hipStream_t stream) {
  const float* query     = (const float*)d_in[0];
  const float* value     = (const float*)d_in[1];
  const float* query_pos = (const float*)d_in[2];
  const float* refpts    = (const float*)d_in[3];
  const float* W_off     = (const float*)d_in[5];
  const float* b_off     = (const float*)d_in[6];
  const float* W_attn    = (const float*)d_in[7];
  const float* b_attn    = (const float*)d_in[8];
  const float* W_val     = (const float*)d_in[9];
  const float* b_val     = (const float*)d_in[10];
  const float* W_out     = (const float*)d_in[11];
  const float* b_out     = (const float*)d_in[12];
  float* out = (float*)d_out;

  char* ws = (char*)d_ws;
  u16* v_ws = (u16*)ws;                                   // 13,613,056 B
  u16* wcat = (u16*)(ws + 13613056);                      //    393,216 B
  u16* wval = (u16*)(ws + 13613056 + 393216);             //    131,072 B
  u16* wout = (u16*)(ws + 13613056 + 393216 + 131072);    //    131,072 B

  k_prep<<<dim3(80 * 8), dim3(64), 0, stream>>>(W_off, W_attn, W_val, W_out,
                                                wcat, wval, wout);
  k_valproj<<<dim3((ROWS_V + 63) / 64), dim3(256), 0, stream>>>(value, b_val, wval, v_ws);
  k_attn<<<dim3(BSB * NQq / MQ), dim3(512), 0, stream>>>(
      query, query_pos, refpts, b_off, b_attn, b_out, wcat, wout, v_ws, out);
}